// Round 7
// baseline (530.977 us; speedup 1.0000x reference)
//
#include <hip/hip_runtime.h>
#include <hip/hip_bf16.h>
#include <math.h>

#define D_MODEL 512
#define D_FF    2048
#define N_HEADS 8
#define D_HEAD  64
#define BATCH   4
#define SEQ     2048
#define NROWS   (BATCH * SEQ)   // 8192
#define LN_EPS  1e-6f

typedef __attribute__((ext_vector_type(8))) short s8b;   // 8 bf16 in 4 VGPRs
typedef __attribute__((ext_vector_type(4))) float f4;
typedef unsigned int u32;
typedef unsigned short u16;

__device__ inline u16 f2bf(float f) {
    u32 u = __float_as_uint(f);
    return (u16)((u + 0x7fffu + ((u >> 16) & 1u)) >> 16);
}
__device__ inline float bf2f(u16 h) {
    return __uint_as_float(((u32)h) << 16);
}
__device__ inline u16 f2bf_hw(float f) {
    __hip_bfloat16 hb = __float2bfloat16(f);
    return *reinterpret_cast<u16*>(&hb);
}

__device__ inline f4 mfma16(s8b a, s8b b, f4 c) {
    return __builtin_amdgcn_mfma_f32_16x16x32_bf16(a, b, c, 0, 0, 0);
}

// async global->LDS, 16B per lane; LDS dest = base + lane*16 (hardware)
__device__ inline void gload16(const u16* g, u16* lds) {
    __builtin_amdgcn_global_load_lds(
        (const __attribute__((address_space(1))) unsigned int*)g,
        (__attribute__((address_space(3))) unsigned int*)lds, 16, 0, 0);
}

// ---------------------------------------------------------------------------
// LayerNorm (ddof=1, /(sigma+eps)), fp32 in -> bf16 out
// ---------------------------------------------------------------------------
__global__ __launch_bounds__(256) void ln_kernel(
    const float* __restrict__ in, const float* __restrict__ gamma,
    const float* __restrict__ beta, u16* __restrict__ out)
{
    const int row = blockIdx.x;
    const int t = threadIdx.x;
    const float* x = in + (size_t)row * D_MODEL;

    float2 v = *(const float2*)(x + t * 2);
    float s = v.x + v.y, ss = v.x * v.x + v.y * v.y;
    #pragma unroll
    for (int m = 1; m < 64; m <<= 1) { s += __shfl_xor(s, m); ss += __shfl_xor(ss, m); }
    __shared__ float red[8];
    const int wid = t >> 6;
    if ((t & 63) == 0) { red[wid] = s; red[wid + 4] = ss; }
    __syncthreads();
    const float st  = red[0] + red[1] + red[2] + red[3];
    const float sst = red[4] + red[5] + red[6] + red[7];
    const float mu  = st / (float)D_MODEL;
    float var = fmaxf((sst - (float)D_MODEL * mu * mu) / (float)(D_MODEL - 1), 0.f);
    const float inv = 1.f / (sqrtf(var) + LN_EPS);
    const float2 g = *(const float2*)(gamma + t * 2);
    const float2 b = *(const float2*)(beta + t * 2);
    u32 o = (u32)f2bf(g.x * (v.x - mu) * inv + b.x)
          | ((u32)f2bf(g.y * (v.y - mu) * inv + b.y) << 16);
    *(u32*)(out + (size_t)row * D_MODEL + t * 2) = o;
}

// ---------------------------------------------------------------------------
// mask int32 [B,S,S] -> bit words [B,S,S/32]
// ---------------------------------------------------------------------------
__global__ __launch_bounds__(256) void packmask_kernel(
    const int* __restrict__ mask, u32* __restrict__ bits)
{
    const int w = blockIdx.x * 256 + threadIdx.x;
    const int* p = mask + (size_t)w * 32;
    u32 b = 0;
    #pragma unroll
    for (int i = 0; i < 8; ++i) {
        int4 v = *(const int4*)(p + i * 4);
        b |= (v.x ? 1u : 0u) << (i * 4 + 0);
        b |= (v.y ? 1u : 0u) << (i * 4 + 1);
        b |= (v.z ? 1u : 0u) << (i * 4 + 2);
        b |= (v.w ? 1u : 0u) << (i * 4 + 3);
    }
    bits[w] = b;
}

// ---------------------------------------------------------------------------
// W [K][N] fp32 -> Wh,Wl [N][K] bf16 (transposed, hi/lo split)
// ---------------------------------------------------------------------------
__global__ __launch_bounds__(256) void splitw_kernel(
    const float* __restrict__ W, u16* __restrict__ Wh, u16* __restrict__ Wl,
    int K, int N)
{
    __shared__ float tile[32][33];
    const int k0 = blockIdx.x * 32, n0 = blockIdx.y * 32;
    const int t = threadIdx.x;
    const int r = t >> 3, c4 = (t & 7) * 4;
    *(float4*)&tile[r][c4] = *(const float4*)(W + (size_t)(k0 + r) * N + n0 + c4);
    __syncthreads();
    u16 hh[4], ll[4];
    #pragma unroll
    for (int j = 0; j < 4; ++j) {
        float v = tile[c4 + j][r];
        hh[j] = f2bf(v);
        ll[j] = f2bf(v - bf2f(hh[j]));
    }
    size_t o = (size_t)(n0 + r) * K + k0 + c4;
    *(u32*)(Wh + o)     = (u32)hh[0] | ((u32)hh[1] << 16);
    *(u32*)(Wh + o + 2) = (u32)hh[2] | ((u32)hh[3] << 16);
    *(u32*)(Wl + o)     = (u32)ll[0] | ((u32)ll[1] << 16);
    *(u32*)(Wl + o + 2) = (u32)ll[2] | ((u32)ll[3] << 16);
}

// ---------------------------------------------------------------------------
// MFMA GEMM: C[M,N] = A[M,K](bf16) @ (Wh+Wl)[K,N] + bias, epilogue by MODE.
// Wh/Wl given as [N][K]. 128x128 tile, BK=64, 4 waves (2x2), 64x64 per wave.
// MODE 0: Q/K scatter bf16 [B,H,S,64]; MODE 1: V scatter bf16 [B,H,64,S];
// MODE 2: relu bf16 [M][N];          MODE 3: fp32 [M][N] + resid.
// LDS k-block XOR swizzle (pre-swizzled global src, linear LDS dest).
// launch_bounds (256,3): LDS 48KB allows 3 blocks/CU (144<=160KB); ~145 regs
// estimated, under the ~170 cap 12 waves/CU needs. If counters show scratch
// spill, revert to (256,2).
// ---------------------------------------------------------------------------
template<int MODE>
__global__ __launch_bounds__(256, 3) void gemm_kernel(
    const u16* __restrict__ A, const u16* __restrict__ Bh,
    const u16* __restrict__ Bl, const float* __restrict__ bias,
    const float* __restrict__ resid, void* __restrict__ Cv,
    int M, int N, int K)
{
    __shared__ u16 As[128 * 64];
    __shared__ u16 Bhs[128 * 64];
    __shared__ u16 Bls[128 * 64];

    const int tid = threadIdx.x;
    const int lane = tid & 63;
    const int wv = tid >> 6;
    const int wr = wv >> 1, wc = wv & 1;
    const int g = lane >> 4, l15 = lane & 15;
    const int bm = blockIdx.x * 128, bn = blockIdx.y * 128;

    const int srow = lane >> 3;                 // 0..7
    const int scol = ((lane & 7) ^ srow) * 8;   // swizzled 8-el k block

    f4 acc[4][4];
    #pragma unroll
    for (int i = 0; i < 4; ++i)
        #pragma unroll
        for (int j = 0; j < 4; ++j) acc[i][j] = (f4){0.f, 0.f, 0.f, 0.f};

    for (int kt = 0; kt < K; kt += 64) {
        #pragma unroll
        for (int i = 0; i < 4; ++i) {
            const int r0 = wv * 32 + i * 8;
            gload16(A  + (size_t)(bm + r0 + srow) * K + kt + scol, As  + r0 * 64);
            gload16(Bh + (size_t)(bn + r0 + srow) * K + kt + scol, Bhs + r0 * 64);
            gload16(Bl + (size_t)(bn + r0 + srow) * K + kt + scol, Bls + r0 * 64);
        }
        __syncthreads();
        #pragma unroll
        for (int kh = 0; kh < 2; ++kh) {
            s8b af[4], bhf[4], blf[4];
            #pragma unroll
            for (int rb = 0; rb < 4; ++rb) {
                const int row = wr * 64 + rb * 16 + l15;
                af[rb] = *(const s8b*)&As[row * 64 + ((kh * 4 + g) ^ (row & 7)) * 8];
            }
            #pragma unroll
            for (int cf = 0; cf < 4; ++cf) {
                const int row = wc * 64 + cf * 16 + l15;
                const int ko = ((kh * 4 + g) ^ (row & 7)) * 8;
                bhf[cf] = *(const s8b*)&Bhs[row * 64 + ko];
                blf[cf] = *(const s8b*)&Bls[row * 64 + ko];
            }
            #pragma unroll
            for (int rb = 0; rb < 4; ++rb)
                #pragma unroll
                for (int cf = 0; cf < 4; ++cf) {
                    acc[rb][cf] = mfma16(af[rb], bhf[cf], acc[rb][cf]);
                    acc[rb][cf] = mfma16(af[rb], blf[cf], acc[rb][cf]);
                }
        }
        __syncthreads();
    }

    #pragma unroll
    for (int rb = 0; rb < 4; ++rb)
        #pragma unroll
        for (int cf = 0; cf < 4; ++cf) {
            const int col = bn + wc * 64 + cf * 16 + l15;
            const float bv = bias[col];
            #pragma unroll
            for (int r = 0; r < 4; ++r) {
                const int row = bm + wr * 64 + rb * 16 + 4 * g + r;
                float v = acc[rb][cf][r] + bv;
                if (MODE == 0) {
                    const int b_ = row >> 11, s_ = row & (SEQ - 1);
                    const int h_ = col >> 6, d_ = col & 63;
                    ((u16*)Cv)[(((size_t)(b_ * N_HEADS + h_) * SEQ + s_) << 6) + d_] = f2bf(v);
                } else if (MODE == 1) {
                    const int b_ = row >> 11, s_ = row & (SEQ - 1);
                    const int h_ = col >> 6, d_ = col & 63;
                    ((u16*)Cv)[(((size_t)(b_ * N_HEADS + h_) * 64 + d_) << 11) + s_] = f2bf(v);
                } else if (MODE == 2) {
                    ((u16*)Cv)[(size_t)row * N + col] = f2bf(fmaxf(v, 0.f));
                } else {
                    ((float*)Cv)[(size_t)row * N + col] = v + resid[(size_t)row * N + col];
                }
            }
        }
}

// ---------------------------------------------------------------------------
// MFMA flash attention, KV-split edition.
// Block = 64 q-rows of one (b,h), 256 threads / 4 waves:
//   wave w: row-group (w&1)*32, KV half (w>>1) of [0,2048).
// Fixed softmax shift m=0 makes partials LINEAR: o=(o0+o1)/(l0+l1) exactly;
// upper-half waves pass partials to lower-half waves through LDS at the end.
// Grid 1024 blocks -> 4 blocks/CU (vs 2 before): occupancy 21% -> ~50%.
// K,V fragments straight from global (L2-resident, XCD-chunked: 4 heads/XCD).
// ---------------------------------------------------------------------------
__global__ __launch_bounds__(256, 4) void flash_kernel(
    const u16* __restrict__ Q,   // [B,H,S,64]
    const u16* __restrict__ Kg,  // [B,H,S,64]
    const u16* __restrict__ Vt,  // [B,H,64,S]
    const u32* __restrict__ mbits, // [B,S,64]
    u16* __restrict__ ctx)       // [B,S,512]
{
    // Qs: [64][72] u16 (9216 B) | Ps: 4 waves x [32][72] u16 (18432 B)
    // combine phase overlays the whole region with float[2*64*41] (20992 B)
    __shared__ __align__(16) u16 smem[13824];   // 27648 B
    u16* Qs = smem;
    u16* Ps = smem + 64 * 72;

    const int tid = threadIdx.x;
    const int lane = tid & 63;
    const int w = tid >> 6;
    const int g = lane >> 4, l15 = lane & 15;
    const int rowgrp = (w & 1) * 32;
    const int kvbase = (w >> 1) * (SEQ / 2);

    const int bid = blockIdx.x;
    const int local = bid >> 3;                    // 0..127
    const int bh = (bid & 7) * 4 + (local >> 5);   // 4 heads per XCD chunk
    const int qt = local & 31;
    const int q0 = qt * 64;
    const int b_ = bh >> 3, h_ = bh & 7;

    const u16* Qb = Q  + (size_t)bh * SEQ * 64;
    const u16* Kb = Kg + (size_t)bh * SEQ * 64;
    const u16* Vb = Vt + (size_t)bh * 64 * SEQ;

    #pragma unroll
    for (int i = 0; i < 2; ++i) {
        const int c = i * 256 + tid;            // 512 chunks of 8 els
        const int row = c >> 3, cb = (c & 7) * 8;
        *(s8b*)&Qs[row * 72 + cb] = *(const s8b*)(Qb + (size_t)(q0 + row) * 64 + cb);
    }
    __syncthreads();

    s8b qf[2][2];
    #pragma unroll
    for (int rb = 0; rb < 2; ++rb)
        #pragma unroll
        for (int kh = 0; kh < 2; ++kh)
            qf[rb][kh] = *(const s8b*)&Qs[(rowgrp + rb * 16 + l15) * 72 + kh * 32 + g * 8];

    f4 o[2][4];
    float lsum[2][4];
    #pragma unroll
    for (int rb = 0; rb < 2; ++rb) {
        #pragma unroll
        for (int df = 0; df < 4; ++df) o[rb][df] = (f4){0.f, 0.f, 0.f, 0.f};
        #pragma unroll
        for (int r = 0; r < 4; ++r) lsum[rb][r] = 0.f;
    }

    const int psbase = w * 32 * 72;   // wave-private Ps region

    for (int it = 0; it < (SEQ / 2) / 64; ++it) {
        const int kv0 = kvbase + it * 64;
        f4 s[2][4];
        #pragma unroll
        for (int rb = 0; rb < 2; ++rb)
            #pragma unroll
            for (int cf = 0; cf < 4; ++cf) s[rb][cf] = (f4){0.f, 0.f, 0.f, 0.f};

        #pragma unroll
        for (int kh = 0; kh < 2; ++kh) {
            s8b kf[4];
            #pragma unroll
            for (int cf = 0; cf < 4; ++cf)
                kf[cf] = *(const s8b*)(Kb + (size_t)(kv0 + cf * 16 + l15) * 64 + kh * 32 + g * 8);
            #pragma unroll
            for (int rb = 0; rb < 2; ++rb)
                #pragma unroll
                for (int cf = 0; cf < 4; ++cf)
                    s[rb][cf] = mfma16(qf[rb][kh], kf[cf], s[rb][cf]);
        }

        // softmax numerator (fixed shift m=0): p = exp2(s * 0.125 * log2e)
        #pragma unroll
        for (int rb = 0; rb < 2; ++rb)
            #pragma unroll
            for (int r = 0; r < 4; ++r) {
                const int qrow = q0 + rowgrp + rb * 16 + 4 * g + r;
                const uint2 mw = *(const uint2*)(mbits + ((size_t)b_ * SEQ + qrow) * 64 + (kv0 >> 5));
                const int prow = psbase + (rb * 16 + 4 * g + r) * 72;
                #pragma unroll
                for (int cf = 0; cf < 4; ++cf) {
                    const u32 word = (cf < 2) ? mw.x : mw.y;
                    const u32 bit = (word >> ((cf & 1) * 16 + l15)) & 1u;
                    float p = bit ? exp2f(s[rb][cf][r] * 0.18033688011117310f) : 0.f;
                    lsum[rb][r] += p;
                    Ps[prow + cf * 16 + l15] = f2bf_hw(p);
                }
            }
        asm volatile("s_waitcnt lgkmcnt(0)" ::: "memory");

        #pragma unroll
        for (int kh = 0; kh < 2; ++kh) {
            s8b pf[2], vf[4];
            #pragma unroll
            for (int rb = 0; rb < 2; ++rb)
                pf[rb] = *(const s8b*)&Ps[psbase + (rb * 16 + l15) * 72 + kh * 32 + g * 8];
            #pragma unroll
            for (int df = 0; df < 4; ++df)
                vf[df] = *(const s8b*)(Vb + (size_t)(df * 16 + l15) * SEQ + kv0 + kh * 32 + g * 8);
            #pragma unroll
            for (int rb = 0; rb < 2; ++rb)
                #pragma unroll
                for (int df = 0; df < 4; ++df)
                    o[rb][df] = mfma16(pf[rb], vf[df], o[rb][df]);
        }
    }

    // ---- combine the two KV halves (exact: fixed-shift partials are linear)
    float* combf = (float*)smem;
    __syncthreads();                       // everyone done with Qs/Ps
    if (w >= 2) {
        const int base = ((w - 2) * 64 + lane) * 41;
        #pragma unroll
        for (int rb = 0; rb < 2; ++rb)
            #pragma unroll
            for (int df = 0; df < 4; ++df)
                #pragma unroll
                for (int r = 0; r < 4; ++r)
                    combf[base + (rb * 4 + df) * 4 + r] = o[rb][df][r];
        #pragma unroll
        for (int rb = 0; rb < 2; ++rb)
            #pragma unroll
            for (int r = 0; r < 4; ++r)
                combf[base + 32 + rb * 4 + r] = lsum[rb][r];
    }
    __syncthreads();
    if (w < 2) {
        const int base = (w * 64 + lane) * 41;
        #pragma unroll
        for (int rb = 0; rb < 2; ++rb)
            #pragma unroll
            for (int df = 0; df < 4; ++df)
                #pragma unroll
                for (int r = 0; r < 4; ++r)
                    o[rb][df][r] += combf[base + (rb * 4 + df) * 4 + r];
        #pragma unroll
        for (int rb = 0; rb < 2; ++rb)
            #pragma unroll
            for (int r = 0; r < 4; ++r)
                lsum[rb][r] += combf[base + 32 + rb * 4 + r];

        #pragma unroll
        for (int rb = 0; rb < 2; ++rb)
            #pragma unroll
            for (int r = 0; r < 4; ++r) {
                float L = lsum[rb][r];
                L += __shfl_xor(L, 1); L += __shfl_xor(L, 2);
                L += __shfl_xor(L, 4); L += __shfl_xor(L, 8);
                const float invl = 1.f / L;
                const int qrow = q0 + rowgrp + rb * 16 + 4 * g + r;
                #pragma unroll
                for (int df = 0; df < 4; ++df)
                    ctx[((size_t)b_ * SEQ + qrow) * D_MODEL + h_ * 64 + df * 16 + l15] =
                        f2bf(o[rb][df][r] * invl);
            }
    }
}

// ---------------------------------------------------------------------------
// Orchestration. Workspace (70 MiB used):
//  [0,8)    h (bf16 LN out, reused)       [8,16) Qb  [16,24) Kb  [24,32) Vt
//  [32,40)  ctx bf16                      [8,40) hid bf16 (overlays after Wo)
//  [40,56)  y fp32                        [56,58) mask bits
//  [58,70)  split weights bf16
// ---------------------------------------------------------------------------
extern "C" void kernel_launch(void* const* d_in, const int* in_sizes, int n_in,
                              void* d_out, int out_size, void* d_ws, size_t ws_size,
                              hipStream_t stream)
{
    const float* x      = (const float*)d_in[0];
    const int*   mask   = (const int*)  d_in[1];
    const float* gamma1 = (const float*)d_in[2];
    const float* beta1  = (const float*)d_in[3];
    const float* Wq = (const float*)d_in[4];  const float* bq = (const float*)d_in[5];
    const float* Wk = (const float*)d_in[6];  const float* bk = (const float*)d_in[7];
    const float* Wv = (const float*)d_in[8];  const float* bv = (const float*)d_in[9];
    const float* Wo = (const float*)d_in[10]; const float* bo = (const float*)d_in[11];
    const float* gamma2 = (const float*)d_in[12];
    const float* beta2  = (const float*)d_in[13];
    const float* W1 = (const float*)d_in[14]; const float* b1 = (const float*)d_in[15];
    const float* W2 = (const float*)d_in[16]; const float* b2 = (const float*)d_in[17];
    float* out = (float*)d_out;

    char* ws = (char*)d_ws;
    const size_t MB = 1ull << 20;
    u16* h    = (u16*)(ws);
    u16* Qb   = (u16*)(ws + 8 * MB);
    u16* Kb   = (u16*)(ws + 16 * MB);
    u16* Vtb  = (u16*)(ws + 24 * MB);
    u16* ctx  = (u16*)(ws + 32 * MB);
    u16* hid  = (u16*)(ws + 8 * MB);     // overlays Qb/Kb/Vt/ctx after Wo GEMM
    float* y  = (float*)(ws + 40 * MB);
    u32* mb   = (u32*)(ws + 56 * MB);
    u16* Wqh = (u16*)(ws + 58 * MB);          u16* Wql = (u16*)(ws + 58 * MB + 512 * 1024);
    u16* Wkh = (u16*)(ws + 59 * MB);          u16* Wkl = (u16*)(ws + 59 * MB + 512 * 1024);
    u16* Wvh = (u16*)(ws + 60 * MB);          u16* Wvl = (u16*)(ws + 60 * MB + 512 * 1024);
    u16* Woh = (u16*)(ws + 61 * MB);          u16* Wol = (u16*)(ws + 61 * MB + 512 * 1024);
    u16* W1h = (u16*)(ws + 62 * MB);          u16* W1l = (u16*)(ws + 64 * MB);
    u16* W2h = (u16*)(ws + 66 * MB);          u16* W2l = (u16*)(ws + 68 * MB);

    const dim3 blk(256);
    const dim3 gP(NROWS / 128, D_MODEL / 128);   // (64, 4)
    const dim3 gF(NROWS / 128, D_FF / 128);      // (64, 16)

    packmask_kernel<<<(BATCH * SEQ * SEQ / 32) / 256, blk, 0, stream>>>(mask, mb);
    splitw_kernel<<<dim3(16, 16), blk, 0, stream>>>(Wq, Wqh, Wql, 512, 512);
    splitw_kernel<<<dim3(16, 16), blk, 0, stream>>>(Wk, Wkh, Wkl, 512, 512);
    splitw_kernel<<<dim3(16, 16), blk, 0, stream>>>(Wv, Wvh, Wvl, 512, 512);
    splitw_kernel<<<dim3(16, 16), blk, 0, stream>>>(Wo, Woh, Wol, 512, 512);
    splitw_kernel<<<dim3(16, 64), blk, 0, stream>>>(W1, W1h, W1l, 512, 2048);
    splitw_kernel<<<dim3(64, 16), blk, 0, stream>>>(W2, W2h, W2l, 2048, 512);

    ln_kernel<<<NROWS, blk, 0, stream>>>(x, gamma1, beta1, h);
    gemm_kernel<0><<<gP, blk, 0, stream>>>(h, Wqh, Wql, bq, nullptr, Qb, NROWS, D_MODEL, D_MODEL);
    gemm_kernel<0><<<gP, blk, 0, stream>>>(h, Wkh, Wkl, bk, nullptr, Kb, NROWS, D_MODEL, D_MODEL);
    gemm_kernel<1><<<gP, blk, 0, stream>>>(h, Wvh, Wvl, bv, nullptr, Vtb, NROWS, D_MODEL, D_MODEL);
    flash_kernel<<<1024, blk, 0, stream>>>(Qb, Kb, Vtb, mb, ctx);
    gemm_kernel<3><<<gP, blk, 0, stream>>>(ctx, Woh, Wol, bo, x, y, NROWS, D_MODEL, D_MODEL);
    ln_kernel<<<NROWS, blk, 0, stream>>>(y, gamma2, beta2, h);
    gemm_kernel<2><<<gF, blk, 0, stream>>>(h, W1h, W1l, b1, nullptr, hid, NROWS, D_FF, D_MODEL);
    gemm_kernel<3><<<gP, blk, 0, stream>>>(hid, W2h, W2l, b2, y, out, NROWS, D_MODEL, D_FF);
}

// Round 10
// 472.447 us; speedup vs baseline: 1.1239x; 1.1239x over previous
//
#include <hip/hip_runtime.h>
#include <hip/hip_bf16.h>
#include <math.h>

#define D_MODEL 512
#define D_FF    2048
#define N_HEADS 8
#define D_HEAD  64
#define BATCH   4
#define SEQ     2048
#define NROWS   (BATCH * SEQ)   // 8192
#define LN_EPS  1e-6f

typedef __attribute__((ext_vector_type(8))) short s8b;   // 8 bf16 in 4 VGPRs
typedef __attribute__((ext_vector_type(4))) float f4;
typedef unsigned int u32;
typedef unsigned short u16;

__device__ inline u16 f2bf(float f) {
    u32 u = __float_as_uint(f);
    return (u16)((u + 0x7fffu + ((u >> 16) & 1u)) >> 16);
}
__device__ inline float bf2f(u16 h) {
    return __uint_as_float(((u32)h) << 16);
}
__device__ inline u16 f2bf_hw(float f) {
    __hip_bfloat16 hb = __float2bfloat16(f);
    return *reinterpret_cast<u16*>(&hb);
}

__device__ inline f4 mfma16(s8b a, s8b b, f4 c) {
    return __builtin_amdgcn_mfma_f32_16x16x32_bf16(a, b, c, 0, 0, 0);
}

// async global->LDS, 16B per lane; LDS dest = base + lane*16 (hardware)
__device__ inline void gload16(const u16* g, u16* lds) {
    __builtin_amdgcn_global_load_lds(
        (const __attribute__((address_space(1))) unsigned int*)g,
        (__attribute__((address_space(3))) unsigned int*)lds, 16, 0, 0);
}

// ---------------------------------------------------------------------------
// LayerNorm (ddof=1, /(sigma+eps)), fp32 in -> bf16 out
// ---------------------------------------------------------------------------
__global__ __launch_bounds__(256) void ln_kernel(
    const float* __restrict__ in, const float* __restrict__ gamma,
    const float* __restrict__ beta, u16* __restrict__ out)
{
    const int row = blockIdx.x;
    const int t = threadIdx.x;
    const float* x = in + (size_t)row * D_MODEL;

    float2 v = *(const float2*)(x + t * 2);
    float s = v.x + v.y, ss = v.x * v.x + v.y * v.y;
    #pragma unroll
    for (int m = 1; m < 64; m <<= 1) { s += __shfl_xor(s, m); ss += __shfl_xor(ss, m); }
    __shared__ float red[8];
    const int wid = t >> 6;
    if ((t & 63) == 0) { red[wid] = s; red[wid + 4] = ss; }
    __syncthreads();
    const float st  = red[0] + red[1] + red[2] + red[3];
    const float sst = red[4] + red[5] + red[6] + red[7];
    const float mu  = st / (float)D_MODEL;
    float var = fmaxf((sst - (float)D_MODEL * mu * mu) / (float)(D_MODEL - 1), 0.f);
    const float inv = 1.f / (sqrtf(var) + LN_EPS);
    const float2 g = *(const float2*)(gamma + t * 2);
    const float2 b = *(const float2*)(beta + t * 2);
    u32 o = (u32)f2bf(g.x * (v.x - mu) * inv + b.x)
          | ((u32)f2bf(g.y * (v.y - mu) * inv + b.y) << 16);
    *(u32*)(out + (size_t)row * D_MODEL + t * 2) = o;
}

// ---------------------------------------------------------------------------
// mask int32 [B,S,S] -> bit words [B,S,S/32]
// ---------------------------------------------------------------------------
__global__ __launch_bounds__(256) void packmask_kernel(
    const int* __restrict__ mask, u32* __restrict__ bits)
{
    const int w = blockIdx.x * 256 + threadIdx.x;
    const int* p = mask + (size_t)w * 32;
    u32 b = 0;
    #pragma unroll
    for (int i = 0; i < 8; ++i) {
        int4 v = *(const int4*)(p + i * 4);
        b |= (v.x ? 1u : 0u) << (i * 4 + 0);
        b |= (v.y ? 1u : 0u) << (i * 4 + 1);
        b |= (v.z ? 1u : 0u) << (i * 4 + 2);
        b |= (v.w ? 1u : 0u) << (i * 4 + 3);
    }
    bits[w] = b;
}

// ---------------------------------------------------------------------------
// W [K][N] fp32 -> Wh,Wl [N][K] bf16 (transposed, hi/lo split)
// ---------------------------------------------------------------------------
__global__ __launch_bounds__(256) void splitw_kernel(
    const float* __restrict__ W, u16* __restrict__ Wh, u16* __restrict__ Wl,
    int K, int N)
{
    __shared__ float tile[32][33];
    const int k0 = blockIdx.x * 32, n0 = blockIdx.y * 32;
    const int t = threadIdx.x;
    const int r = t >> 3, c4 = (t & 7) * 4;
    *(float4*)&tile[r][c4] = *(const float4*)(W + (size_t)(k0 + r) * N + n0 + c4);
    __syncthreads();
    u16 hh[4], ll[4];
    #pragma unroll
    for (int j = 0; j < 4; ++j) {
        float v = tile[c4 + j][r];
        hh[j] = f2bf(v);
        ll[j] = f2bf(v - bf2f(hh[j]));
    }
    size_t o = (size_t)(n0 + r) * K + k0 + c4;
    *(u32*)(Wh + o)     = (u32)hh[0] | ((u32)hh[1] << 16);
    *(u32*)(Wh + o + 2) = (u32)hh[2] | ((u32)hh[3] << 16);
    *(u32*)(Wl + o)     = (u32)ll[0] | ((u32)ll[1] << 16);
    *(u32*)(Wl + o + 2) = (u32)ll[2] | ((u32)ll[3] << 16);
}

// ---------------------------------------------------------------------------
// MFMA GEMM: C[M,N] = A[M,K](bf16) @ (Wh+Wl)[K,N] + bias, epilogue by MODE.
// 128x128 tile, BK=64, 4 waves (2x2), 64x64 per wave. (256,3) was neutral
// in r7 (rest-of-pipeline 327->330us) -- kept.
// ---------------------------------------------------------------------------
template<int MODE>
__global__ __launch_bounds__(256, 3) void gemm_kernel(
    const u16* __restrict__ A, const u16* __restrict__ Bh,
    const u16* __restrict__ Bl, const float* __restrict__ bias,
    const float* __restrict__ resid, void* __restrict__ Cv,
    int M, int N, int K)
{
    __shared__ u16 As[128 * 64];
    __shared__ u16 Bhs[128 * 64];
    __shared__ u16 Bls[128 * 64];

    const int tid = threadIdx.x;
    const int lane = tid & 63;
    const int wv = tid >> 6;
    const int wr = wv >> 1, wc = wv & 1;
    const int g = lane >> 4, l15 = lane & 15;
    const int bm = blockIdx.x * 128, bn = blockIdx.y * 128;

    const int srow = lane >> 3;                 // 0..7
    const int scol = ((lane & 7) ^ srow) * 8;   // swizzled 8-el k block

    f4 acc[4][4];
    #pragma unroll
    for (int i = 0; i < 4; ++i)
        #pragma unroll
        for (int j = 0; j < 4; ++j) acc[i][j] = (f4){0.f, 0.f, 0.f, 0.f};

    for (int kt = 0; kt < K; kt += 64) {
        #pragma unroll
        for (int i = 0; i < 4; ++i) {
            const int r0 = wv * 32 + i * 8;
            gload16(A  + (size_t)(bm + r0 + srow) * K + kt + scol, As  + r0 * 64);
            gload16(Bh + (size_t)(bn + r0 + srow) * K + kt + scol, Bhs + r0 * 64);
            gload16(Bl + (size_t)(bn + r0 + srow) * K + kt + scol, Bls + r0 * 64);
        }
        __syncthreads();
        #pragma unroll
        for (int kh = 0; kh < 2; ++kh) {
            s8b af[4], bhf[4], blf[4];
            #pragma unroll
            for (int rb = 0; rb < 4; ++rb) {
                const int row = wr * 64 + rb * 16 + l15;
                af[rb] = *(const s8b*)&As[row * 64 + ((kh * 4 + g) ^ (row & 7)) * 8];
            }
            #pragma unroll
            for (int cf = 0; cf < 4; ++cf) {
                const int row = wc * 64 + cf * 16 + l15;
                const int ko = ((kh * 4 + g) ^ (row & 7)) * 8;
                bhf[cf] = *(const s8b*)&Bhs[row * 64 + ko];
                blf[cf] = *(const s8b*)&Bls[row * 64 + ko];
            }
            #pragma unroll
            for (int rb = 0; rb < 4; ++rb)
                #pragma unroll
                for (int cf = 0; cf < 4; ++cf) {
                    acc[rb][cf] = mfma16(af[rb], bhf[cf], acc[rb][cf]);
                    acc[rb][cf] = mfma16(af[rb], blf[cf], acc[rb][cf]);
                }
        }
        __syncthreads();
    }

    #pragma unroll
    for (int rb = 0; rb < 4; ++rb)
        #pragma unroll
        for (int cf = 0; cf < 4; ++cf) {
            const int col = bn + wc * 64 + cf * 16 + l15;
            const float bv = bias[col];
            #pragma unroll
            for (int r = 0; r < 4; ++r) {
                const int row = bm + wr * 64 + rb * 16 + 4 * g + r;
                float v = acc[rb][cf][r] + bv;
                if (MODE == 0) {
                    const int b_ = row >> 11, s_ = row & (SEQ - 1);
                    const int h_ = col >> 6, d_ = col & 63;
                    ((u16*)Cv)[(((size_t)(b_ * N_HEADS + h_) * SEQ + s_) << 6) + d_] = f2bf(v);
                } else if (MODE == 1) {
                    const int b_ = row >> 11, s_ = row & (SEQ - 1);
                    const int h_ = col >> 6, d_ = col & 63;
                    ((u16*)Cv)[(((size_t)(b_ * N_HEADS + h_) * 64 + d_) << 11) + s_] = f2bf(v);
                } else if (MODE == 2) {
                    ((u16*)Cv)[(size_t)row * N + col] = f2bf(fmaxf(v, 0.f));
                } else {
                    ((float*)Cv)[(size_t)row * N + col] = v + resid[(size_t)row * N + col];
                }
            }
        }
}

// ---------------------------------------------------------------------------
// MFMA flash attention — r3 shape (128-row q-tiles, 512 blocks, proven
// 153us / 14MB fetch) + software-pipelined loads:
//   * kf double-buffered: issued one FULL iteration before use
//   * vf + mask issued at body top, consumed ~700cy later (after QK+softmax)
//   * next-iter kf issued before softmax, flies across iteration boundary
// Math identical to r3/r7 (same accumulation order) -> absmax unchanged.
// VGPR ~240 is free: 512 blocks = 2 blocks/CU fixed; <=256 VGPR keeps 8 waves/CU.
// ---------------------------------------------------------------------------
struct FlashCtx {
    const u16* Kb; const u16* Vb; const u32* Mb; u16* Ps;
    int psbase, l15, g;
};

__device__ __forceinline__ void flash_body(
    const FlashCtx& cx, int it,
    const s8b (&qf)[2][2], const s8b (&kfC)[2][4], s8b (&kfN)[2][4],
    f4 (&o)[2][4], float (&lsum)[2][4])
{
    const int kv0 = it * 64;
    const int kvn = (it == 31) ? 0 : kv0 + 64;   // wrap: harmless re-read
    const int l15 = cx.l15, g = cx.g;

    // issue current-iter V loads (consumed at PV, ~700cy away)
    s8b vf[2][4];
    #pragma unroll
    for (int kh = 0; kh < 2; ++kh)
        #pragma unroll
        for (int df = 0; df < 4; ++df)
            vf[kh][df] = *(const s8b*)(cx.Vb + (size_t)(df * 16 + l15) * SEQ + kv0 + kh * 32 + g * 8);

    // issue current-iter mask loads (consumed at softmax)
    uint2 mw[2][4];
    #pragma unroll
    for (int rb = 0; rb < 2; ++rb)
        #pragma unroll
        for (int r = 0; r < 4; ++r)
            mw[rb][r] = *(const uint2*)(cx.Mb + (rb * 16 + 4 * g + r) * 64 + (kv0 >> 5));

    // QK^T with K prefetched LAST iteration (latency fully hidden)
    f4 s[2][4];
    #pragma unroll
    for (int rb = 0; rb < 2; ++rb)
        #pragma unroll
        for (int cf = 0; cf < 4; ++cf) s[rb][cf] = (f4){0.f, 0.f, 0.f, 0.f};
    #pragma unroll
    for (int kh = 0; kh < 2; ++kh)
        #pragma unroll
        for (int rb = 0; rb < 2; ++rb)
            #pragma unroll
            for (int cf = 0; cf < 4; ++cf)
                s[rb][cf] = mfma16(qf[rb][kh], kfC[kh][cf], s[rb][cf]);

    // prefetch NEXT iteration's K (consumed next body, full-iter distance)
    #pragma unroll
    for (int kh = 0; kh < 2; ++kh)
        #pragma unroll
        for (int cf = 0; cf < 4; ++cf)
            kfN[kh][cf] = *(const s8b*)(cx.Kb + (size_t)(kvn + cf * 16 + l15) * 64 + kh * 32 + g * 8);

    // softmax numerator (fixed shift m=0): p = exp2(s * 0.125 * log2e)
    #pragma unroll
    for (int rb = 0; rb < 2; ++rb)
        #pragma unroll
        for (int r = 0; r < 4; ++r) {
            const int prow = cx.psbase + (rb * 16 + 4 * g + r) * 72;
            #pragma unroll
            for (int cf = 0; cf < 4; ++cf) {
                const u32 word = (cf < 2) ? mw[rb][r].x : mw[rb][r].y;
                const u32 bit = (word >> ((cf & 1) * 16 + l15)) & 1u;
                float p = bit ? exp2f(s[rb][cf][r] * 0.18033688011117310f) : 0.f;
                lsum[rb][r] += p;
                cx.Ps[prow + cf * 16 + l15] = f2bf_hw(p);
            }
        }
    asm volatile("s_waitcnt lgkmcnt(0)" ::: "memory");

    // PV with vf issued at body top
    #pragma unroll
    for (int kh = 0; kh < 2; ++kh) {
        s8b pf[2];
        pf[0] = *(const s8b*)&cx.Ps[cx.psbase + l15 * 72 + kh * 32 + g * 8];
        pf[1] = *(const s8b*)&cx.Ps[cx.psbase + (16 + l15) * 72 + kh * 32 + g * 8];
        #pragma unroll
        for (int rb = 0; rb < 2; ++rb)
            #pragma unroll
            for (int df = 0; df < 4; ++df)
                o[rb][df] = mfma16(pf[rb], vf[kh][df], o[rb][df]);
    }
}

__global__ __launch_bounds__(256, 2) void flash_kernel(
    const u16* __restrict__ Q,   // [B,H,S,64]
    const u16* __restrict__ Kg,  // [B,H,S,64]
    const u16* __restrict__ Vt,  // [B,H,64,S]
    const u32* __restrict__ mbits, // [B,S,64]
    u16* __restrict__ ctx)       // [B,S,512]
{
    __shared__ __align__(16) u16 Qs[128 * 72];
    __shared__ __align__(16) u16 Ps[128 * 72];

    const int tid = threadIdx.x;
    const int lane = tid & 63;
    const int w = tid >> 6;
    const int g = lane >> 4, l15 = lane & 15;

    const int bid = blockIdx.x;
    const int local = bid >> 3;                    // 0..63
    const int bh = (bid & 7) * 4 + (local >> 4);   // 4 heads per XCD chunk
    const int qt = local & 15;
    const int q0 = qt * 128;
    const int b_ = bh >> 3, h_ = bh & 7;

    const u16* Qb = Q  + (size_t)bh * SEQ * 64;
    const u16* Kb = Kg + (size_t)bh * SEQ * 64;
    const u16* Vb = Vt + (size_t)bh * 64 * SEQ;
    const u32* Mb = mbits + ((size_t)b_ * SEQ + q0 + w * 32) * 64;

    #pragma unroll
    for (int i = 0; i < 4; ++i) {
        const int c = i * 256 + tid;            // 1024 chunks of 8 els
        const int row = c >> 3, cb = (c & 7) * 8;
        *(s8b*)&Qs[row * 72 + cb] = *(const s8b*)(Qb + (size_t)(q0 + row) * 64 + cb);
    }
    __syncthreads();

    s8b qf[2][2];
    #pragma unroll
    for (int rb = 0; rb < 2; ++rb)
        #pragma unroll
        for (int kh = 0; kh < 2; ++kh)
            qf[rb][kh] = *(const s8b*)&Qs[(w * 32 + rb * 16 + l15) * 72 + kh * 32 + g * 8];

    f4 o[2][4];
    float lsum[2][4];
    #pragma unroll
    for (int rb = 0; rb < 2; ++rb) {
        #pragma unroll
        for (int df = 0; df < 4; ++df) o[rb][df] = (f4){0.f, 0.f, 0.f, 0.f};
        #pragma unroll
        for (int r = 0; r < 4; ++r) lsum[rb][r] = 0.f;
    }

    FlashCtx cx;
    cx.Kb = Kb; cx.Vb = Vb; cx.Mb = Mb; cx.Ps = Ps;
    cx.psbase = w * 32 * 72; cx.l15 = l15; cx.g = g;

    // prologue: load K for it=0
    s8b kfA[2][4], kfB[2][4];
    #pragma unroll
    for (int kh = 0; kh < 2; ++kh)
        #pragma unroll
        for (int cf = 0; cf < 4; ++cf)
            kfA[kh][cf] = *(const s8b*)(Kb + (size_t)(cf * 16 + l15) * 64 + kh * 32 + g * 8);

    #pragma unroll 1
    for (int it = 0; it < 32; it += 2) {
        flash_body(cx, it,     qf, kfA, kfB, o, lsum);
        flash_body(cx, it + 1, qf, kfB, kfA, o, lsum);
    }

    // epilogue: reduce lsum across the 16 tx lanes, normalize, write ctx
    #pragma unroll
    for (int rb = 0; rb < 2; ++rb)
        #pragma unroll
        for (int r = 0; r < 4; ++r) {
            float L = lsum[rb][r];
            L += __shfl_xor(L, 1); L += __shfl_xor(L, 2);
            L += __shfl_xor(L, 4); L += __shfl_xor(L, 8);
            const float invl = 1.f / L;
            const int qrow = q0 + w * 32 + rb * 16 + 4 * g + r;
            #pragma unroll
            for (int df = 0; df < 4; ++df)
                ctx[((size_t)b_ * SEQ + qrow) * D_MODEL + h_ * 64 + df * 16 + l15] =
                    f2bf(o[rb][df][r] * invl);
        }
}

// ---------------------------------------------------------------------------
// Orchestration. Workspace (70 MiB used):
//  [0,8)    h (bf16 LN out, reused)       [8,16) Qb  [16,24) Kb  [24,32) Vt
//  [32,40)  ctx bf16                      [8,40) hid bf16 (overlays after Wo)
//  [40,56)  y fp32                        [56,58) mask bits
//  [58,70)  split weights bf16
// ---------------------------------------------------------------------------
extern "C" void kernel_launch(void* const* d_in, const int* in_sizes, int n_in,
                              void* d_out, int out_size, void* d_ws, size_t ws_size,
                              hipStream_t stream)
{
    const float* x      = (const float*)d_in[0];
    const int*   mask   = (const int*)  d_in[1];
    const float* gamma1 = (const float*)d_in[2];
    const float* beta1  = (const float*)d_in[3];
    const float* Wq = (const float*)d_in[4];  const float* bq = (const float*)d_in[5];
    const float* Wk = (const float*)d_in[6];  const float* bk = (const float*)d_in[7];
    const float* Wv = (const float*)d_in[8];  const float* bv = (const float*)d_in[9];
    const float* Wo = (const float*)d_in[10]; const float* bo = (const float*)d_in[11];
    const float* gamma2 = (const float*)d_in[12];
    const float* beta2  = (const float*)d_in[13];
    const float* W1 = (const float*)d_in[14]; const float* b1 = (const float*)d_in[15];
    const float* W2 = (const float*)d_in[16]; const float* b2 = (const float*)d_in[17];
    float* out = (float*)d_out;

    char* ws = (char*)d_ws;
    const size_t MB = 1ull << 20;
    u16* h    = (u16*)(ws);
    u16* Qb   = (u16*)(ws + 8 * MB);
    u16* Kb   = (u16*)(ws + 16 * MB);
    u16* Vtb  = (u16*)(ws + 24 * MB);
    u16* ctx  = (u16*)(ws + 32 * MB);
    u16* hid  = (u16*)(ws + 8 * MB);     // overlays Qb/Kb/Vt/ctx after Wo GEMM
    float* y  = (float*)(ws + 40 * MB);
    u32* mb   = (u32*)(ws + 56 * MB);
    u16* Wqh = (u16*)(ws + 58 * MB);          u16* Wql = (u16*)(ws + 58 * MB + 512 * 1024);
    u16* Wkh = (u16*)(ws + 59 * MB);          u16* Wkl = (u16*)(ws + 59 * MB + 512 * 1024);
    u16* Wvh = (u16*)(ws + 60 * MB);          u16* Wvl = (u16*)(ws + 60 * MB + 512 * 1024);
    u16* Woh = (u16*)(ws + 61 * MB);          u16* Wol = (u16*)(ws + 61 * MB + 512 * 1024);
    u16* W1h = (u16*)(ws + 62 * MB);          u16* W1l = (u16*)(ws + 64 * MB);
    u16* W2h = (u16*)(ws + 66 * MB);          u16* W2l = (u16*)(ws + 68 * MB);

    const dim3 blk(256);
    const dim3 gP(NROWS / 128, D_MODEL / 128);   // (64, 4)
    const dim3 gF(NROWS / 128, D_FF / 128);      // (64, 16)

    packmask_kernel<<<(BATCH * SEQ * SEQ / 32) / 256, blk, 0, stream>>>(mask, mb);
    splitw_kernel<<<dim3(16, 16), blk, 0, stream>>>(Wq, Wqh, Wql, 512, 512);
    splitw_kernel<<<dim3(16, 16), blk, 0, stream>>>(Wk, Wkh, Wkl, 512, 512);
    splitw_kernel<<<dim3(16, 16), blk, 0, stream>>>(Wv, Wvh, Wvl, 512, 512);
    splitw_kernel<<<dim3(16, 16), blk, 0, stream>>>(Wo, Woh, Wol, 512, 512);
    splitw_kernel<<<dim3(16, 64), blk, 0, stream>>>(W1, W1h, W1l, 512, 2048);
    splitw_kernel<<<dim3(64, 16), blk, 0, stream>>>(W2, W2h, W2l, 2048, 512);

    ln_kernel<<<NROWS, blk, 0, stream>>>(x, gamma1, beta1, h);
    gemm_kernel<0><<<gP, blk, 0, stream>>>(h, Wqh, Wql, bq, nullptr, Qb, NROWS, D_MODEL, D_MODEL);
    gemm_kernel<0><<<gP, blk, 0, stream>>>(h, Wkh, Wkl, bk, nullptr, Kb, NROWS, D_MODEL, D_MODEL);
    gemm_kernel<1><<<gP, blk, 0, stream>>>(h, Wvh, Wvl, bv, nullptr, Vtb, NROWS, D_MODEL, D_MODEL);
    flash_kernel<<<512, blk, 0, stream>>>(Qb, Kb, Vtb, mb, ctx);
    gemm_kernel<3><<<gP, blk, 0, stream>>>(ctx, Woh, Wol, bo, x, y, NROWS, D_MODEL, D_MODEL);
    ln_kernel<<<NROWS, blk, 0, stream>>>(y, gamma2, beta2, h);
    gemm_kernel<2><<<gF, blk, 0, stream>>>(h, W1h, W1l, b1, nullptr, hid, NROWS, D_FF, D_MODEL);
    gemm_kernel<3><<<gP, blk, 0, stream>>>(hid, W2h, W2l, b2, y, out, NROWS, D_MODEL, D_FF);
}